// Round 1
// baseline (86.715 us; speedup 1.0000x reference)
//
#include <hip/hip_runtime.h>
#include <math.h>

#define PUPIL 256
#define N_BINS 8
#define BATCH 16

__constant__ int PHASE_NS_C[N_BINS] = {1024, 988, 952, 918, 886, 856, 828, 802};

typedef short bf16x8 __attribute__((ext_vector_type(8)));
typedef float f32x4  __attribute__((ext_vector_type(4)));
typedef int   i32x4  __attribute__((ext_vector_type(4)));

#define MFMA16(a, b, c) __builtin_amdgcn_mfma_f32_16x16x32_bf16((a), (b), (c), 0, 0, 0)

__device__ __forceinline__ short f2bf(float f) {   // RNE float->bf16
  unsigned u = __float_as_uint(f);
  u += 0x7FFFu + ((u >> 16) & 1u);
  return (short)(u >> 16);
}
__device__ __forceinline__ bf16x8 neg8(bf16x8 v) {
  i32x4 t = __builtin_bit_cast(i32x4, v);
  t ^= (int)0x80008000;
  return __builtin_bit_cast(bf16x8, t);
}

// ---------------------------------------------------------------------------
// PSF[u,v] = | sum_{y,x} P[y,x] W[y,u] W[x,v] |^2 ; W[n,k]=e^{-2pi i (k-32) n/N}
// kv-split fusion: each block owns a 32-kv half of one (b,bin).
// R5 change: 512-thread blocks (8 waves = 2 waves/SIMD, was 1/SIMD) -- pure
// TLP, same total work; pvbuf aliases Pr (LDS 82->73 KB); wprep via float
// range reduction (exact: |(k-32)n| <= 8160 < 2^24) instead of int-div+libm.
// MFMA 16x16x32 bf16 (verified R4): A[m=lane&15][k=quad*8+j] 16B contig,
// B-frag = B^T row, D: col=lane&15, row=quad*4+reg.
// ---------------------------------------------------------------------------

// W_t[bin][k=64][n=256] bf16
__global__ void wprep(short* __restrict__ Wr_t, short* __restrict__ Wi_t) {
  int idx = blockIdx.x * 256 + threadIdx.x;   // 131072
  int n   = idx & 255;
  int k   = (idx >> 8) & 63;
  int bin = idx >> 14;
  int N = PHASE_NS_C[bin];
  // m/N == frac((k-32)*n / N); product is exact in f32 (<2^24), fast divide
  // err ~2 ulp -> angle err ~1e-5 rad, far below bf16 quantization (4e-3).
  float f = __fdividef((float)((k - 32) * n), (float)N);
  float rev = f - floorf(f);                  // [0,1)
  float s, c;
  __sincosf(-6.283185307179586f * rev, &s, &c);
  Wr_t[idx] = f2bf(c);
  Wi_t[idx] = f2bf(s);
}

// grid (2 khalf, 8 bin, 16 b) = 256 blocks, 512 threads (8 waves, 2/SIMD)
__global__ __launch_bounds__(512, 2) void fused(
    const float* __restrict__ opd, const float* __restrict__ obsc,
    const float* __restrict__ lambdas,
    const short* __restrict__ Wr_t, const short* __restrict__ Wi_t,
    float* __restrict__ psf_raw, float* __restrict__ sums)
{
  const int tid = threadIdx.x;
  const int khalf = blockIdx.x, bin = blockIdx.y, b = blockIdx.z;
  const int bb = b * N_BINS + bin;
  const float w0 = 6.283185307179586f / lambdas[bin];

  // LDS layout (73.0 KB): Pr[256][40] | Pi[256][40] | Gr[32][264] | Gi[32][264] | red[8]
  // pvbuf[64][33] (8448 B) aliases Pr: Pr is dead after the G-write barrier.
  __shared__ __align__(16) char smem[20480 * 2 + 16896 * 2 + 32];
  short* Pr    = (short*)smem;
  short* Pi    = (short*)(smem + 20480);
  short* Gr    = (short*)(smem + 40960);
  short* Gi    = (short*)(smem + 57856);
  float* red   = (float*)(smem + 74752);
  float* pvbuf = (float*)smem;

  const int wave = tid >> 6, lane = tid & 63;
  const int lr = lane & 15, lq = lane >> 4;

  // ---------------- stage 1: G^T[32 kv][256 y], K = x ----------------
  f32x4 aR[2][2], aI[2][2];
  #pragma unroll
  for (int m = 0; m < 2; ++m)
    #pragma unroll
    for (int t = 0; t < 2; ++t) { aR[m][t] = (f32x4)0.0f; aI[m][t] = (f32x4)0.0f; }

  const int gy0 = tid >> 2;          // 0..127
  const int gx  = (tid & 3) * 8;     // 0,8,16,24
  const short* wr0 = Wr_t + ((size_t)bin * 64 + khalf * 32 + lr) * 256 + lq * 8;
  const short* wi0 = Wi_t + ((size_t)bin * 64 + khalf * 32 + lr) * 256 + lq * 8;

  for (int xc = 0; xc < 8; ++xc) {
    const int xb = xc * 32;
    // generate P chunk [256 y][32 x]: each thread 2 y-rows x 8 x
    bf16x8 vr[2], vi[2];
    #pragma unroll
    for (int i = 0; i < 2; ++i) {
      const int y = gy0 + i * 128;
      const float* orow = opd + ((size_t)b * PUPIL + y) * PUPIL + xb + gx;
      const float* brow = obsc + (size_t)y * PUPIL + xb + gx;
      float od[8], ob[8];
      *(float4*)&od[0] = *(const float4*)orow;
      *(float4*)&od[4] = *(const float4*)(orow + 4);
      *(float4*)&ob[0] = *(const float4*)brow;
      *(float4*)&ob[4] = *(const float4*)(brow + 4);
      #pragma unroll
      for (int j = 0; j < 8; ++j) {
        float s, c;
        __sincosf(w0 * od[j], &s, &c);
        vr[i][j] = f2bf(c * ob[j]);
        vi[i][j] = f2bf(s * ob[j]);
      }
    }
    // W fragments for this chunk (independent global loads; issue early)
    const bf16x8 w_r0  = *(const bf16x8*)(wr0 + xb);
    const bf16x8 w_r1  = *(const bf16x8*)(wr0 + 16 * 256 + xb);
    const bf16x8 w_i0  = *(const bf16x8*)(wi0 + xb);
    const bf16x8 w_i1  = *(const bf16x8*)(wi0 + 16 * 256 + xb);
    const bf16x8 nw_i0 = neg8(w_i0);
    const bf16x8 nw_i1 = neg8(w_i1);
    __syncthreads();                 // previous chunk's P reads complete
    #pragma unroll
    for (int i = 0; i < 2; ++i) {
      const int y = gy0 + i * 128;
      *(bf16x8*)&Pr[y * 40 + gx] = vr[i];
      *(bf16x8*)&Pi[y * 40 + gx] = vi[i];
    }
    __syncthreads();                 // P chunk visible

    for (int t = 0; t < 2; ++t) {    // wave owns y-strip wave*32..+31
      const int y = wave * 32 + t * 16 + lr;
      const bf16x8 pr = *(const bf16x8*)&Pr[y * 40 + lq * 8];
      const bf16x8 pi = *(const bf16x8*)&Pi[y * 40 + lq * 8];
      aR[0][t] = MFMA16(w_r0,  pr, aR[0][t]);
      aR[0][t] = MFMA16(nw_i0, pi, aR[0][t]);
      aI[0][t] = MFMA16(w_r0,  pi, aI[0][t]);
      aI[0][t] = MFMA16(w_i0,  pr, aI[0][t]);
      aR[1][t] = MFMA16(w_r1,  pr, aR[1][t]);
      aR[1][t] = MFMA16(nw_i1, pi, aR[1][t]);
      aI[1][t] = MFMA16(w_r1,  pi, aI[1][t]);
      aI[1][t] = MFMA16(w_i1,  pr, aI[1][t]);
    }
  }

  // write G^T to LDS (bf16); D: row(lq*4+r)=kv-local, col(lr)=y-local
  #pragma unroll
  for (int m = 0; m < 2; ++m)
    #pragma unroll
    for (int t = 0; t < 2; ++t) {
      const int y = wave * 32 + t * 16 + lr;
      #pragma unroll
      for (int r = 0; r < 4; ++r) {
        const int kvl = m * 16 + lq * 4 + r;
        Gr[kvl * 264 + y] = f2bf(aR[m][t][r]);
        Gi[kvl * 264 + y] = f2bf(aI[m][t][r]);
      }
    }
  __syncthreads();                   // G visible; Pr/Pi now dead (pvbuf safe)

  // ---------------- stage 2: H^T[32 kv][64 ku], K = y ----------------
  // 8 waves x 1 D-tile each: kv-tile m2 = wave>>2, ku-tile kut = wave&3
  const int m2  = wave >> 2;
  const int kut = wave & 3;
  f32x4 hR = (f32x4)0.0f, hI = (f32x4)0.0f;

  for (int yc = 0; yc < 8; ++yc) {
    const int yb2 = yc * 32;
    const size_t wo = ((size_t)bin * 64 + kut * 16 + lr) * 256 + yb2 + lq * 8;
    const bf16x8 w_r = *(const bf16x8*)(Wr_t + wo);   // B-frag: n=ku
    const bf16x8 w_i = *(const bf16x8*)(Wi_t + wo);
    const bf16x8 g_r = *(const bf16x8*)&Gr[(m2 * 16 + lr) * 264 + yb2 + lq * 8];
    const bf16x8 g_i = *(const bf16x8*)&Gi[(m2 * 16 + lr) * 264 + yb2 + lq * 8];
    const bf16x8 ng_i = neg8(g_i);
    hR = MFMA16(g_r,  w_r, hR);
    hR = MFMA16(ng_i, w_i, hR);
    hI = MFMA16(g_r,  w_i, hI);
    hI = MFMA16(g_i,  w_r, hI);
  }

  // |H|^2, block partial sum, transpose via LDS (pvbuf aliases Pr), store
  float pv[4];
  float lsum = 0.f;
  #pragma unroll
  for (int r = 0; r < 4; ++r) {
    pv[r] = hR[r] * hR[r] + hI[r] * hI[r];
    lsum += pv[r];
  }
  #pragma unroll
  for (int off = 32; off > 0; off >>= 1) lsum += __shfl_down(lsum, off);
  if (lane == 0) red[wave] = lsum;

  const int u = kut * 16 + lr;                 // D col -> ku
  #pragma unroll
  for (int r = 0; r < 4; ++r)
    pvbuf[u * 33 + m2 * 16 + lq * 4 + r] = pv[r];
  __syncthreads();

  if (tid == 0)
    sums[bb * 2 + khalf] = red[0] + red[1] + red[2] + red[3]
                         + red[4] + red[5] + red[6] + red[7];

  #pragma unroll
  for (int k2 = 0; k2 < 4; ++k2) {
    const int i = tid + k2 * 512;               // 0..2047
    const int uu = i >> 5, vl = i & 31;
    psf_raw[(size_t)bb * 4096 + uu * 64 + khalf * 32 + vl] = pvbuf[uu * 33 + vl];
  }
}

// combine: scale = sed[bin]/(S0+S1); out = sum_bin scale*pv. 256 blocks.
__global__ void combine(const float* __restrict__ psf_raw,
                        const float* __restrict__ sums,
                        const float* __restrict__ sed,
                        float* __restrict__ out) {
  __shared__ float sc[N_BINS];
  const int blk = blockIdx.x;
  const int b = blk >> 4;                       // 16 blocks per image
  const int px = (blk & 15) * 256 + threadIdx.x;
  if (threadIdx.x < N_BINS) {
    const int bb = b * N_BINS + threadIdx.x;
    sc[threadIdx.x] = sed[threadIdx.x] / (sums[bb * 2] + sums[bb * 2 + 1]);
  }
  __syncthreads();
  float acc = 0.f;
  #pragma unroll
  for (int bin = 0; bin < N_BINS; ++bin)
    acc += sc[bin] * psf_raw[(size_t)(b * N_BINS + bin) * 4096 + px];
  out[b * 4096 + px] = acc;
}

extern "C" void kernel_launch(void* const* d_in, const int* in_sizes, int n_in,
                              void* d_out, int out_size, void* d_ws, size_t ws_size,
                              hipStream_t stream) {
  const float* opd     = (const float*)d_in[0];
  const float* obsc    = (const float*)d_in[1];
  const float* lambdas = (const float*)d_in[2];
  const float* sed     = (const float*)d_in[3];
  float* out = (float*)d_out;

  // ws: Wr_t 256KB | Wi_t 256KB | psf_raw 2MB | sums 1KB
  short* Wr_t   = (short*)d_ws;
  short* Wi_t   = Wr_t + (size_t)N_BINS * 64 * 256;
  float* psf_raw = (float*)(Wi_t + (size_t)N_BINS * 64 * 256);
  float* sums    = psf_raw + (size_t)BATCH * N_BINS * 4096;

  wprep<<<512, 256, 0, stream>>>(Wr_t, Wi_t);
  fused<<<dim3(2, N_BINS, BATCH), 512, 0, stream>>>(opd, obsc, lambdas,
                                                    Wr_t, Wi_t, psf_raw, sums);
  combine<<<256, 256, 0, stream>>>(psf_raw, sums, sed, out);
}